// Round 6
// baseline (724.301 us; speedup 1.0000x reference)
//
#include <hip/hip_runtime.h>
#include <math.h>

// Problem constants
#define F_DIM 64
#define N_NODES 64
#define T_LEN 24
#define N_HEADS 8
#define BATCH 16
#define E_DIM 4096          // F_DIM * N_NODES
#define HD 512              // E / N_HEADS
#define QKV_N 12288         // 3*E
#define MB 384              // T_LEN * BATCH
#define TS 23               // T_LEN - 1
#define MP 368              // TS * BATCH
#define MPAD 384            // padded row count for both GEMMs

typedef unsigned short ushort_t;
typedef short bf16x8 __attribute__((ext_vector_type(8)));
typedef float f32x4 __attribute__((ext_vector_type(4)));

// fp32 -> bf16, round-half-up (add 0x8000, truncate)
__device__ inline ushort_t f2bf(float f) {
    return (ushort_t)((__float_as_uint(f) + 0x8000u) >> 16);
}

// async global->LDS, 16B per lane. LDS dest = uniform base + lane*16.
__device__ inline void async_load16(const ushort_t* g, ushort_t* lds) {
    __builtin_amdgcn_global_load_lds(
        (const __attribute__((address_space(1))) unsigned int*)g,
        (__attribute__((address_space(3))) unsigned int*)lds,
        16, 0, 0);
}

// dot of 2 packed bf16 pairs (a,c are uints holding 2 bf16 each)
__device__ inline float bdot2(unsigned int a, unsigned int c) {
    float a0 = __uint_as_float(a << 16), a1 = __uint_as_float(a & 0xFFFF0000u);
    float c0 = __uint_as_float(c << 16), c1 = __uint_as_float(c & 0xFFFF0000u);
    return a0 * c0 + a1 * c1;
}

// ---------------------------------------------------------------------------
// Kernel 0: xt[t*16+b, f*64+n] = bf16(x[b, f, t, n])   (float4 -> 4x bf16)
// ---------------------------------------------------------------------------
__global__ void k_transpose(const float* __restrict__ x, ushort_t* __restrict__ xt) {
    int m = blockIdx.x;              // t*16 + b
    int t = m >> 4, b = m & 15;
    const float* xb = x + (size_t)b * (F_DIM * T_LEN * N_NODES) + (size_t)t * N_NODES;
    ushort_t* row = xt + (size_t)m * E_DIM;
    for (int e4 = threadIdx.x; e4 < E_DIM / 4; e4 += 256) {
        int e = e4 * 4;
        int f = e >> 6, n = e & 63;
        const float4 v = *(const float4*)&xb[(size_t)f * (T_LEN * N_NODES) + n];
        ushort_t o[4] = {f2bf(v.x), f2bf(v.y), f2bf(v.z), f2bf(v.w)};
        *(uint2*)&row[e] = *(uint2*)o;
    }
}

// ---------------------------------------------------------------------------
// MFMA GEMM, M-full tiling: block tile = 384 (all M) x 64 (N), BK=32.
// 4 waves, each owns 96 rows x 64 cols = 6x4 16x16x32 frags.
// A: bf16 in ws (384 rows). B: fp32 weights -> bf16 via v_perm during staging.
// blockIdx.z = K-chunk of kc cols; raw partial stores (bias in consumers).
// ---------------------------------------------------------------------------
__global__ __launch_bounds__(256) void k_gemm_mfma(
    const ushort_t* __restrict__ A, const float* __restrict__ B,
    float* __restrict__ P, int N, int K, int kc)
{
    __shared__ __align__(16) ushort_t As[384 * 32];   // 24 KB
    __shared__ __align__(16) ushort_t Bs[64 * 32];    // 4 KB
    const int tid  = threadIdx.x;
    const int wave = tid >> 6, lane = tid & 63;
    const int lr = lane & 15, lq = lane >> 4;
    const int n0 = blockIdx.x * 64;
    const int kz = blockIdx.z * kc;

    f32x4 acc[6][4];
    #pragma unroll
    for (int i = 0; i < 6; ++i)
        #pragma unroll
        for (int j = 0; j < 4; ++j)
            acc[i][j] = (f32x4){0.f, 0.f, 0.f, 0.f};

    // A staging: 384x32 bf16 = 24 wave-instructions; 6 per wave.
    const int rb = lane >> 2, kp = (lane & 3) * 8;
    const ushort_t* gA[6];
    ushort_t* lA[6];
    #pragma unroll
    for (int s = 0; s < 6; ++s) {
        int r = (wave * 6 + s) * 16 + rb;
        gA[s] = A + (size_t)r * K + kp;
        lA[s] = As + (wave * 6 + s) * 512;
    }

    for (int k0 = kz; k0 < kz + kc; k0 += 32) {
        #pragma unroll
        for (int s = 0; s < 6; ++s) async_load16(gA[s] + k0, lA[s]);
        // B: 64x32 fp32 = 512 float4; 2 per thread, convert via v_perm
        #pragma unroll
        for (int s = 0; s < 2; ++s) {
            int e4  = tid + s * 256;
            int row = e4 >> 3;
            int kq  = (e4 & 7) * 4;
            const float4 v = *(const float4*)(B + (size_t)(n0 + row) * K + k0 + kq);
            unsigned int ux = __float_as_uint(v.x) + 0x8000u;
            unsigned int uy = __float_as_uint(v.y) + 0x8000u;
            unsigned int uz = __float_as_uint(v.z) + 0x8000u;
            unsigned int uw = __float_as_uint(v.w) + 0x8000u;
            unsigned int p0 = __builtin_amdgcn_perm(uy, ux, 0x07060302u);
            unsigned int p1 = __builtin_amdgcn_perm(uw, uz, 0x07060302u);
            *(uint2*)&Bs[row * 32 + kq] = make_uint2(p0, p1);
        }
        __syncthreads();
        bf16x8 af[6], bfr[4];
        #pragma unroll
        for (int i = 0; i < 6; ++i)
            af[i] = *(const bf16x8*)&As[(wave * 96 + i * 16 + lr) * 32 + lq * 8];
        #pragma unroll
        for (int j = 0; j < 4; ++j)
            bfr[j] = *(const bf16x8*)&Bs[(j * 16 + lr) * 32 + lq * 8];
        #pragma unroll
        for (int i = 0; i < 6; ++i)
            #pragma unroll
            for (int j = 0; j < 4; ++j)
                acc[i][j] = __builtin_amdgcn_mfma_f32_16x16x32_bf16(af[i], bfr[j], acc[i][j], 0, 0, 0);
        __syncthreads();
    }

    // epilogue: raw partial store (all 384 rows valid; no guards)
    float* Pz = P + (size_t)blockIdx.z * MPAD * N;
    #pragma unroll
    for (int i = 0; i < 6; ++i) {
        int m = wave * 96 + i * 16 + lq * 4;
        #pragma unroll
        for (int r = 0; r < 4; ++r) {
            #pragma unroll
            for (int j = 0; j < 4; ++j)
                Pz[(size_t)(m + r) * N + n0 + j * 16 + lr] = acc[i][j][r];
        }
    }
}

// ---------------------------------------------------------------------------
// k_attn: per (b,h). Consumes RAW QKV partials P[s][384][12288] + bias:
//   1) stage Q,K (sum partials + bqkv -> bf16) into LDS
//   2) wave-per-dot scores; prefix softmax;
//      wbar[t,k] = (1/(t+1)) sum_{q<=t} E[q,k]/S[q,t]
//   3) cbar[t*16+b, h*512+d] = bf16( sum_k wbar[t,k] * v[k,d] ),
//      v reduced from partials + bias on the fly, acc[23] in registers.
// ---------------------------------------------------------------------------
__global__ __launch_bounds__(512) void k_attn(const float* __restrict__ P,
                                              const float* __restrict__ bqkv,
                                              ushort_t* __restrict__ cbar, int S) {
    int bh = blockIdx.x;             // b*8 + h
    int b = bh >> 3, h = bh & 7;
    __shared__ __align__(16) ushort_t qs[T_LEN * HD];  // 24 KB bf16
    __shared__ __align__(16) ushort_t ks[T_LEN * HD];  // 24 KB bf16
    __shared__ float ss[T_LEN][25];
    __shared__ float isv[T_LEN][25];
    __shared__ float wbs[TS][T_LEN];
    int tid = threadIdx.x, wave = tid >> 6, lane = tid & 63;
    const size_t pstride = (size_t)MPAD * QKV_N;

    // stage Q,K reduced + biased -> bf16 LDS
    for (int i = tid; i < T_LEN * HD; i += 512) {
        int t = i >> 9, d = i & 511;
        size_t rq = (size_t)(t * BATCH + b) * QKV_N + h * HD + d;
        float q = bqkv[h * HD + d], k = bqkv[E_DIM + h * HD + d];
        for (int s = 0; s < S; ++s) {
            q += P[s * pstride + rq];
            k += P[s * pstride + rq + E_DIM];
        }
        qs[i] = f2bf(q);
        ks[i] = f2bf(k);
    }
    __syncthreads();

    const float scale = 0.044194173824159216f;   // 1/sqrt(512)
    for (int p = wave; p < T_LEN * T_LEN; p += 8) {
        int qi = p / 24, ki = p - qi * 24;
        uint4 qv = *(const uint4*)&qs[qi * HD + lane * 8];
        uint4 kv = *(const uint4*)&ks[ki * HD + lane * 8];
        float s = bdot2(qv.x, kv.x) + bdot2(qv.y, kv.y)
                + bdot2(qv.z, kv.z) + bdot2(qv.w, kv.w);
        #pragma unroll
        for (int off = 32; off > 0; off >>= 1) s += __shfl_xor(s, off);
        if (lane == 0) {
            s *= scale;
            if (ki <= qi) s += 1.f;      // tril_add (includes diagonal)
            ss[qi][ki] = s;
        }
    }
    __syncthreads();
    if (tid < T_LEN) {
        int q = tid;
        float M = -1e30f;
        for (int k = 0; k < T_LEN; ++k) M = fmaxf(M, ss[q][k]);
        float run = 0.f;
        for (int k = 0; k < T_LEN; ++k) {
            float e = __expf(ss[q][k] - M);
            ss[q][k] = e;
            run += e;
            isv[q][k] = 1.f / run;   // 1 / S[q, t=k]
        }
    }
    __syncthreads();
    for (int p = tid; p < TS * T_LEN; p += 512) {
        int t = p / 24, k = p - t * 24;
        float w = 0.f;
        if (k <= t) {
            float sum = 0.f;
            for (int q = 0; q <= t; ++q) sum += ss[q][k] * isv[q][t];
            w = sum / (float)(t + 1);
        }
        wbs[t][k] = w;
    }
    __syncthreads();

    // cbar: thread owns one d; V reduced from partials on the fly
    int d = tid;                        // 512 threads == HD
    float acc[TS];
    #pragma unroll
    for (int t = 0; t < TS; ++t) acc[t] = 0.f;
    const float bv = bqkv[2 * E_DIM + h * HD + d];
    for (int k = 0; k < T_LEN; ++k) {
        size_t rv = (size_t)(k * BATCH + b) * QKV_N + 2 * E_DIM + h * HD + d;
        float v = bv;
        for (int s = 0; s < S; ++s) v += P[s * pstride + rv];
        #pragma unroll
        for (int t = 0; t < TS; ++t) acc[t] += wbs[t][k] * v;   // wbs=0 for k>t
    }
    #pragma unroll
    for (int t = 0; t < TS; ++t)
        cbar[(size_t)(t * BATCH + b) * E_DIM + h * HD + d] = f2bf(acc[t]);
}

// ---------------------------------------------------------------------------
// k_final: ps = sum_s P[s][tb] + bo;  out[b,f,t+1,n] = relu(ps[f*64+:]@Wfc^T + bfc)
// ---------------------------------------------------------------------------
__global__ void k_final(const float* __restrict__ P, const float* __restrict__ bo,
                        const float* __restrict__ Wfc, const float* __restrict__ bfc,
                        float* __restrict__ out, int S) {
    int tb = blockIdx.x;             // t*16 + b
    int t = tb >> 4, b = tb & 15;
    __shared__ float ps[E_DIM];      // 16 KB
    __shared__ float wf[64 * 65];    // padded
    __shared__ float bf[64];
    int tid = threadIdx.x;
    const size_t pstride = (size_t)MPAD * E_DIM;
    for (int i = tid; i < E_DIM; i += 256) {
        float v = bo[i];
        for (int s = 0; s < S; ++s) v += P[s * pstride + (size_t)tb * E_DIM + i];
        ps[i] = v;
    }
    for (int i = tid; i < 64 * 64; i += 256) wf[(i >> 6) * 65 + (i & 63)] = Wfc[i];
    if (tid < 64) bf[tid] = bfc[tid];
    __syncthreads();
    for (int p = tid; p < 4096; p += 256) {
        int f = p >> 6, n = p & 63;
        float acc = bf[n];
        #pragma unroll
        for (int g = 0; g < 64; ++g) acc += ps[f * 64 + g] * wf[n * 65 + g];
        out[(size_t)((b * 64 + f) * T_LEN + (t + 1)) * N_NODES + n] = fmaxf(acc, 0.f);
    }
}

// k_first: out[b,f,0,n] = x[b,f,0,n]   (65536 elems, 256 blocks)
__global__ void k_first(const float* __restrict__ x, float* __restrict__ out) {
    int idx = blockIdx.x * 256 + threadIdx.x;
    if (idx >= BATCH * F_DIM * N_NODES) return;
    int b = idx >> 12, f = (idx >> 6) & 63, n = idx & 63;
    size_t o = ((size_t)(b * 64 + f) * T_LEN) * 64 + n;
    out[o] = x[o];
}

extern "C" void kernel_launch(void* const* d_in, const int* in_sizes, int n_in,
                              void* d_out, int out_size, void* d_ws, size_t ws_size,
                              hipStream_t stream) {
    const float* x    = (const float*)d_in[0];
    const float* Wqkv = (const float*)d_in[1];
    const float* bqkv = (const float*)d_in[2];
    const float* Wo   = (const float*)d_in[3];
    const float* bo   = (const float*)d_in[4];
    const float* Wfc  = (const float*)d_in[5];
    const float* bfc  = (const float*)d_in[6];
    float* out = (float*)d_out;

    // ws layout (bytes): xt bf16 | cbar bf16 | pbuf f32 partials (shared
    // by QKV phase then Wo phase)
    char* wsb = (char*)d_ws;
    ushort_t* xt   = (ushort_t*)wsb;                      // 3,145,728
    ushort_t* cbar = (ushort_t*)(wsb + 3145728);          // 3,145,728
    size_t base    = 6291456;
    float*  pbuf   = (float*)(wsb + base);

    const size_t pq = (size_t)MPAD * QKV_N * 4;    // QKV partial: 18.87 MB
    const size_t po = (size_t)MPAD * E_DIM * 4;    // Wo partial:   6.29 MB
    int S = 1;                                      // QKV K-split
    if      (ws_size >= base + 8 * pq) S = 8;
    else if (ws_size >= base + 4 * pq) S = 4;
    else if (ws_size >= base + 2 * pq) S = 2;
    int Swo = 1;                                    // Wo K-split
    if      (ws_size >= base + 16 * po) Swo = 16;
    else if (ws_size >= base + 8 * po)  Swo = 8;
    else if (ws_size >= base + 4 * po)  Swo = 4;

    hipLaunchKernelGGL(k_transpose, dim3(MB), dim3(256), 0, stream, x, xt);

    hipLaunchKernelGGL(k_gemm_mfma, dim3(QKV_N / 64, 1, S), dim3(256), 0, stream,
                       xt, Wqkv, pbuf, QKV_N, E_DIM, E_DIM / S);

    hipLaunchKernelGGL(k_attn, dim3(BATCH * N_HEADS), dim3(512), 0, stream,
                       pbuf, bqkv, cbar, S);

    hipLaunchKernelGGL(k_gemm_mfma, dim3(E_DIM / 64, 1, Swo), dim3(256), 0, stream,
                       cbar, Wo, pbuf, E_DIM, E_DIM, E_DIM / Swo);

    hipLaunchKernelGGL(k_final, dim3(TS * BATCH), dim3(256), 0, stream,
                       pbuf, bo, Wfc, bfc, out, Swo);

    hipLaunchKernelGGL(k_first, dim3((BATCH * F_DIM * N_NODES + 255) / 256), dim3(256), 0, stream, x, out);
}

// Round 7
// 712.305 us; speedup vs baseline: 1.0168x; 1.0168x over previous
//
#include <hip/hip_runtime.h>
#include <math.h>

// Problem constants
#define F_DIM 64
#define N_NODES 64
#define T_LEN 24
#define N_HEADS 8
#define BATCH 16
#define E_DIM 4096          // F_DIM * N_NODES
#define HD 512              // E / N_HEADS
#define QKV_N 12288         // 3*E
#define MB 384              // T_LEN * BATCH
#define TS 23               // T_LEN - 1
#define MP 368              // TS * BATCH
#define MPAD 384            // padded row count for both GEMMs

typedef unsigned short ushort_t;
typedef short bf16x8 __attribute__((ext_vector_type(8)));
typedef float f32x4 __attribute__((ext_vector_type(4)));

// fp32 -> bf16, round-half-up (add 0x8000, truncate)
__device__ inline ushort_t f2bf(float f) {
    return (ushort_t)((__float_as_uint(f) + 0x8000u) >> 16);
}

// 8 fp32 (as uint4 pair) -> bf16x8 via v_perm byte-packing, w/ rounding
__device__ inline bf16x8 cvt8(uint4 u0, uint4 u1) {
    union { unsigned int u[4]; bf16x8 v; } r;
    r.u[0] = __builtin_amdgcn_perm(u0.y + 0x8000u, u0.x + 0x8000u, 0x07060302u);
    r.u[1] = __builtin_amdgcn_perm(u0.w + 0x8000u, u0.z + 0x8000u, 0x07060302u);
    r.u[2] = __builtin_amdgcn_perm(u1.y + 0x8000u, u1.x + 0x8000u, 0x07060302u);
    r.u[3] = __builtin_amdgcn_perm(u1.w + 0x8000u, u1.z + 0x8000u, 0x07060302u);
    return r.v;
}

// dot of 2 packed bf16 pairs (a,c are uints holding 2 bf16 each)
__device__ inline float bdot2(unsigned int a, unsigned int c) {
    float a0 = __uint_as_float(a << 16), a1 = __uint_as_float(a & 0xFFFF0000u);
    float c0 = __uint_as_float(c << 16), c1 = __uint_as_float(c & 0xFFFF0000u);
    return a0 * c0 + a1 * c1;
}

// ---------------------------------------------------------------------------
// Kernel 0: xt[t*16+b, f*64+n] = bf16(x[b, f, t, n])   (float4 -> 4x bf16)
// ---------------------------------------------------------------------------
__global__ void k_transpose(const float* __restrict__ x, ushort_t* __restrict__ xt) {
    int m = blockIdx.x;              // t*16 + b
    int t = m >> 4, b = m & 15;
    const float* xb = x + (size_t)b * (F_DIM * T_LEN * N_NODES) + (size_t)t * N_NODES;
    ushort_t* row = xt + (size_t)m * E_DIM;
    for (int e4 = threadIdx.x; e4 < E_DIM / 4; e4 += 256) {
        int e = e4 * 4;
        int f = e >> 6, n = e & 63;
        const float4 v = *(const float4*)&xb[(size_t)f * (T_LEN * N_NODES) + n];
        ushort_t o[4] = {f2bf(v.x), f2bf(v.y), f2bf(v.z), f2bf(v.w)};
        *(uint2*)&row[e] = *(uint2*)o;
    }
}

// ---------------------------------------------------------------------------
// Barrier-free register-pipelined MFMA GEMM.
// One wave per block (64 thr), no LDS, no __syncthreads. Wave owns a 64x64
// tile: 4x4 16x16x32 frags. A (bf16, L2-resident) and B (fp32 weights ->
// bf16 in-register) loaded straight from global with 2-stage ping-pong
// prefetch -> compiler emits fine-grained vmcnt interleave (AITER pattern).
// blockIdx = (n-tile, m-tile, K-chunk). Raw partial stores; bias downstream.
// ---------------------------------------------------------------------------
__global__ __launch_bounds__(64) void k_gemm_direct(
    const ushort_t* __restrict__ A, const float* __restrict__ B,
    float* __restrict__ P, int N, int K, int kc)
{
    const int lane = threadIdx.x;
    const int lr = lane & 15, lq = lane >> 4;
    const int n0 = blockIdx.x * 64;
    const int m0 = blockIdx.y * 64;
    const int kz = blockIdx.z * kc;

    const ushort_t* Ap[4];
    const float*    Bp[4];
    #pragma unroll
    for (int i = 0; i < 4; ++i)
        Ap[i] = A + (size_t)(m0 + i * 16 + lr) * K + lq * 8;
    #pragma unroll
    for (int j = 0; j < 4; ++j)
        Bp[j] = B + (size_t)(n0 + j * 16 + lr) * K + lq * 8;

    f32x4 acc[4][4];
    #pragma unroll
    for (int i = 0; i < 4; ++i)
        #pragma unroll
        for (int j = 0; j < 4; ++j)
            acc[i][j] = (f32x4){0.f, 0.f, 0.f, 0.f};

    bf16x8 a0[4], a1[4];
    uint4  b0[4][2], b1[4][2];

    // prime set0 @ kz
    #pragma unroll
    for (int i = 0; i < 4; ++i) a0[i] = *(const bf16x8*)(Ap[i] + kz);
    #pragma unroll
    for (int j = 0; j < 4; ++j) {
        b0[j][0] = *(const uint4*)(Bp[j] + kz);
        b0[j][1] = *(const uint4*)(Bp[j] + kz + 4);
    }

    for (int k0 = kz; k0 < kz + kc; k0 += 64) {
        // prefetch set1 @ k0+32 (always in-range: kc is a multiple of 64)
        #pragma unroll
        for (int i = 0; i < 4; ++i) a1[i] = *(const bf16x8*)(Ap[i] + k0 + 32);
        #pragma unroll
        for (int j = 0; j < 4; ++j) {
            b1[j][0] = *(const uint4*)(Bp[j] + k0 + 32);
            b1[j][1] = *(const uint4*)(Bp[j] + k0 + 36);
        }
        // compute set0
        #pragma unroll
        for (int j = 0; j < 4; ++j) {
            bf16x8 bf = cvt8(b0[j][0], b0[j][1]);
            #pragma unroll
            for (int i = 0; i < 4; ++i)
                acc[i][j] = __builtin_amdgcn_mfma_f32_16x16x32_bf16(a0[i], bf, acc[i][j], 0, 0, 0);
        }
        // prefetch set0 @ k0+64 (wrap to kz on final iter; values unused)
        int kn = (k0 + 64 < kz + kc) ? (k0 + 64) : kz;
        #pragma unroll
        for (int i = 0; i < 4; ++i) a0[i] = *(const bf16x8*)(Ap[i] + kn);
        #pragma unroll
        for (int j = 0; j < 4; ++j) {
            b0[j][0] = *(const uint4*)(Bp[j] + kn);
            b0[j][1] = *(const uint4*)(Bp[j] + kn + 4);
        }
        // compute set1
        #pragma unroll
        for (int j = 0; j < 4; ++j) {
            bf16x8 bf = cvt8(b1[j][0], b1[j][1]);
            #pragma unroll
            for (int i = 0; i < 4; ++i)
                acc[i][j] = __builtin_amdgcn_mfma_f32_16x16x32_bf16(a1[i], bf, acc[i][j], 0, 0, 0);
        }
    }

    // epilogue: raw partial store (C/D layout: row = lq*4 + r, col = lr)
    float* Pz = P + (size_t)blockIdx.z * MPAD * N;
    #pragma unroll
    for (int i = 0; i < 4; ++i) {
        int m = m0 + i * 16 + lq * 4;
        #pragma unroll
        for (int r = 0; r < 4; ++r) {
            #pragma unroll
            for (int j = 0; j < 4; ++j)
                Pz[(size_t)(m + r) * N + n0 + j * 16 + lr] = acc[i][j][r];
        }
    }
}

// ---------------------------------------------------------------------------
// k_reduceq: qkvb[m,n] = bf16( sum_s P[s,m,n] + bqkv[n] )   (8 elems/thread)
// ---------------------------------------------------------------------------
__global__ void k_reduceq(const float* __restrict__ P, const float* __restrict__ bias,
                          ushort_t* __restrict__ qkvb, int S) {
    size_t e = ((size_t)blockIdx.x * 256 + threadIdx.x) * 8;   // grid exact
    int n = (int)(e % QKV_N);
    float4 s0 = *(const float4*)(bias + n);
    float4 s1 = *(const float4*)(bias + n + 4);
    const size_t pstride = (size_t)MPAD * QKV_N;
    for (int s = 0; s < S; ++s) {
        const float4 p0 = *(const float4*)(P + s * pstride + e);
        const float4 p1 = *(const float4*)(P + s * pstride + e + 4);
        s0.x += p0.x; s0.y += p0.y; s0.z += p0.z; s0.w += p0.w;
        s1.x += p1.x; s1.y += p1.y; s1.z += p1.z; s1.w += p1.w;
    }
    ushort_t o[8] = {f2bf(s0.x), f2bf(s0.y), f2bf(s0.z), f2bf(s0.w),
                     f2bf(s1.x), f2bf(s1.y), f2bf(s1.z), f2bf(s1.w)};
    *(uint4*)(qkvb + e) = *(const uint4*)o;
}

// ---------------------------------------------------------------------------
// k_attn: per (b,h), reads reduced bf16 qkvb.
//   K,V staged to LDS; Q read direct (L2-hot). Wave-per-dot scores ->
//   prefix softmax -> wbar -> cbar[t*16+b, h*512+d] = bf16(sum_k wbar*v)
// ---------------------------------------------------------------------------
__global__ __launch_bounds__(512) void k_attn(const ushort_t* __restrict__ qkvb,
                                              ushort_t* __restrict__ cbar) {
    int bh = blockIdx.x;             // b*8 + h
    int b = bh >> 3, h = bh & 7;
    __shared__ __align__(16) ushort_t ks[T_LEN * HD];  // 24 KB
    __shared__ __align__(16) ushort_t vs[T_LEN * HD];  // 24 KB
    __shared__ float ss[T_LEN][25];
    __shared__ float isv[T_LEN][25];
    __shared__ float wbs[TS][T_LEN];
    int tid = threadIdx.x, wave = tid >> 6, lane = tid & 63;

    for (int i = tid; i < T_LEN * HD / 8; i += 512) {   // 1536 uint4s
        int t = i >> 6, d8 = (i & 63) * 8;
        size_t base = (size_t)(t * BATCH + b) * QKV_N + h * HD + d8;
        *(uint4*)&ks[t * HD + d8] = *(const uint4*)&qkvb[base + E_DIM];
        *(uint4*)&vs[t * HD + d8] = *(const uint4*)&qkvb[base + 2 * E_DIM];
    }
    __syncthreads();

    const float scale = 0.044194173824159216f;   // 1/sqrt(512)
    for (int p = wave; p < T_LEN * T_LEN; p += 8) {
        int qi = p / 24, ki = p - qi * 24;
        uint4 qv = *(const uint4*)&qkvb[(size_t)(qi * BATCH + b) * QKV_N + h * HD + lane * 8];
        uint4 kv = *(const uint4*)&ks[ki * HD + lane * 8];
        float s = bdot2(qv.x, kv.x) + bdot2(qv.y, kv.y)
                + bdot2(qv.z, kv.z) + bdot2(qv.w, kv.w);
        #pragma unroll
        for (int off = 32; off > 0; off >>= 1) s += __shfl_xor(s, off);
        if (lane == 0) {
            s *= scale;
            if (ki <= qi) s += 1.f;      // tril_add (includes diagonal)
            ss[qi][ki] = s;
        }
    }
    __syncthreads();
    if (tid < T_LEN) {
        int q = tid;
        float M = -1e30f;
        for (int k = 0; k < T_LEN; ++k) M = fmaxf(M, ss[q][k]);
        float run = 0.f;
        for (int k = 0; k < T_LEN; ++k) {
            float e = __expf(ss[q][k] - M);
            ss[q][k] = e;
            run += e;
            isv[q][k] = 1.f / run;   // 1 / S[q, t=k]
        }
    }
    __syncthreads();
    for (int p = tid; p < TS * T_LEN; p += 512) {
        int t = p / 24, k = p - t * 24;
        float w = 0.f;
        if (k <= t) {
            float sum = 0.f;
            for (int q = 0; q <= t; ++q) sum += ss[q][k] * isv[q][t];
            w = sum / (float)(t + 1);
        }
        wbs[t][k] = w;
    }
    __syncthreads();

    int d = tid;                        // 512 threads == HD
    float acc[TS];
    #pragma unroll
    for (int t = 0; t < TS; ++t) acc[t] = 0.f;
    for (int k = 0; k < T_LEN; ++k) {
        float v = __uint_as_float(((unsigned int)vs[k * HD + d]) << 16);
        #pragma unroll
        for (int t = 0; t < TS; ++t) acc[t] += wbs[t][k] * v;   // wbs=0 for k>t
    }
    #pragma unroll
    for (int t = 0; t < TS; ++t)
        cbar[(size_t)(t * BATCH + b) * E_DIM + h * HD + d] = f2bf(acc[t]);
}

// ---------------------------------------------------------------------------
// k_final: ps = sum_s P[s][tb] + bo;  out[b,f,t+1,n] = relu(ps[f*64+:]@Wfc^T + bfc)
// ---------------------------------------------------------------------------
__global__ void k_final(const float* __restrict__ P, const float* __restrict__ bo,
                        const float* __restrict__ Wfc, const float* __restrict__ bfc,
                        float* __restrict__ out, int S) {
    int tb = blockIdx.x;             // t*16 + b
    int t = tb >> 4, b = tb & 15;
    __shared__ float ps[E_DIM];      // 16 KB
    __shared__ float wf[64 * 65];    // padded
    __shared__ float bf[64];
    int tid = threadIdx.x;
    const size_t pstride = (size_t)MPAD * E_DIM;
    for (int i = tid; i < E_DIM; i += 256) {
        float v = bo[i];
        for (int s = 0; s < S; ++s) v += P[s * pstride + (size_t)tb * E_DIM + i];
        ps[i] = v;
    }
    for (int i = tid; i < 64 * 64; i += 256) wf[(i >> 6) * 65 + (i & 63)] = Wfc[i];
    if (tid < 64) bf[tid] = bfc[tid];
    __syncthreads();
    for (int p = tid; p < 4096; p += 256) {
        int f = p >> 6, n = p & 63;
        float acc = bf[n];
        #pragma unroll
        for (int g = 0; g < 64; ++g) acc += ps[f * 64 + g] * wf[n * 65 + g];
        out[(size_t)((b * 64 + f) * T_LEN + (t + 1)) * N_NODES + n] = fmaxf(acc, 0.f);
    }
}

// k_first: out[b,f,0,n] = x[b,f,0,n]   (65536 elems, 256 blocks)
__global__ void k_first(const float* __restrict__ x, float* __restrict__ out) {
    int idx = blockIdx.x * 256 + threadIdx.x;
    if (idx >= BATCH * F_DIM * N_NODES) return;
    int b = idx >> 12, f = (idx >> 6) & 63, n = idx & 63;
    size_t o = ((size_t)(b * 64 + f) * T_LEN) * 64 + n;
    out[o] = x[o];
}

extern "C" void kernel_launch(void* const* d_in, const int* in_sizes, int n_in,
                              void* d_out, int out_size, void* d_ws, size_t ws_size,
                              hipStream_t stream) {
    const float* x    = (const float*)d_in[0];
    const float* Wqkv = (const float*)d_in[1];
    const float* bqkv = (const float*)d_in[2];
    const float* Wo   = (const float*)d_in[3];
    const float* bo   = (const float*)d_in[4];
    const float* Wfc  = (const float*)d_in[5];
    const float* bfc  = (const float*)d_in[6];
    float* out = (float*)d_out;

    // ws layout (bytes): xt bf16 | cbar bf16 | qkvb bf16 | pbuf f32 partials
    char* wsb = (char*)d_ws;
    ushort_t* xt   = (ushort_t*)wsb;                      //  3,145,728
    ushort_t* cbar = (ushort_t*)(wsb + 3145728);          //  3,145,728
    ushort_t* qkvb = (ushort_t*)(wsb + 6291456);          //  9,437,184
    size_t base    = 6291456 + 9437184;
    float*  pbuf   = (float*)(wsb + base);

    const size_t pq = (size_t)MPAD * QKV_N * 4;    // QKV partial: 18.87 MB
    const size_t po = (size_t)MPAD * E_DIM * 4;    // Wo partial:   6.29 MB
    int S = 1;                                      // QKV K-split (kc % 64 == 0)
    if      (ws_size >= base + 4 * pq) S = 4;
    else if (ws_size >= base + 2 * pq) S = 2;
    int Swo = 1;                                    // Wo K-split
    if      (ws_size >= base + 8 * po) Swo = 8;
    else if (ws_size >= base + 4 * po) Swo = 4;

    hipLaunchKernelGGL(k_transpose, dim3(MB), dim3(256), 0, stream, x, xt);

    hipLaunchKernelGGL(k_gemm_direct, dim3(QKV_N / 64, MPAD / 64, S), dim3(64), 0, stream,
                       xt, Wqkv, pbuf, QKV_N, E_DIM, E_DIM / S);
    hipLaunchKernelGGL(k_reduceq, dim3(MPAD * QKV_N / 8 / 256), dim3(256), 0, stream,
                       pbuf, bqkv, qkvb, S);

    hipLaunchKernelGGL(k_attn, dim3(BATCH * N_HEADS), dim3(512), 0, stream, qkvb, cbar);

    hipLaunchKernelGGL(k_gemm_direct, dim3(E_DIM / 64, MPAD / 64, Swo), dim3(64), 0, stream,
                       cbar, Wo, pbuf, E_DIM, E_DIM, E_DIM / Swo);

    hipLaunchKernelGGL(k_final, dim3(TS * BATCH), dim3(256), 0, stream,
                       pbuf, bo, Wfc, bfc, out, Swo);

    hipLaunchKernelGGL(k_first, dim3((BATCH * F_DIM * N_NODES + 255) / 256), dim3(256), 0, stream, x, out);
}